// Round 5
// baseline (85.159 us; speedup 1.0000x reference)
//
#include <hip/hip_runtime.h>
#include <math.h>

#define N_PROP 1000
#define NCLS   91
#define NCM1   90
#define KDET   100
#define SCORE_TH 0.05f
#define NMS_TH   0.5f
#define MIN_SIZE 1.0f
#define BBOX_CLIP 4.135166556742356f  // log(1000/16)

// ws layout: stats f32[2*N_PROP] @ 0   (rowmax, 1/sumexp)

// K1: one wave per row -> softmax stats. (proven R2 pattern)
__global__ __launch_bounds__(256) void stats_kernel(const float* __restrict__ logit,
                                                    float* __restrict__ stats) {
    const int gid  = blockIdx.x * blockDim.x + threadIdx.x;
    const int row  = gid >> 6;
    const int lane = gid & 63;
    if (row >= N_PROP) return;
    const float* p = logit + row * NCLS;
    float l0 = p[lane];                                  // lane < 64 < 91: always valid
    float l1 = (lane + 64 < NCLS) ? p[lane + 64] : -INFINITY;
    float m = fmaxf(l0, l1);
    for (int d = 32; d > 0; d >>= 1) m = fmaxf(m, __shfl_xor(m, d));
    float s = expf(l0 - m) + ((lane + 64 < NCLS) ? expf(l1 - m) : 0.0f);
    for (int d = 32; d > 0; d >>= 1) s += __shfl_xor(s, d);
    if (lane == 0) {
        stats[row] = m;
        stats[N_PROP + row] = 1.0f / s;
    }
}

// K2: one block per class. Decode own column + LDS-atomic compaction +
// rank sort + greedy NMS + output. No global counters, no zero pass.
__global__ __launch_bounds__(128) void class_kernel(
    const float* __restrict__ logit,
    const float* __restrict__ boxreg,
    const float* __restrict__ proposal,
    const int* __restrict__ ih_p,
    const int* __restrict__ iw_p,
    const float* __restrict__ stats,
    float* __restrict__ out) {
    const int cm1 = blockIdx.x;
    const int c   = cm1 + 1;
    const int tid = threadIdx.x;

    __shared__ float  s_key[N_PROP];
    __shared__ int    s_idx[N_PROP];
    __shared__ float4 s_box[N_PROP];
    __shared__ float  s_skey[N_PROP];
    __shared__ float4 s_sbox[N_PROP];
    __shared__ int    s_keep[N_PROP];
    __shared__ int    s_outpos[KDET];
    __shared__ int    s_cnt, s_nout;

    if (tid == 0) s_cnt = 0;
    __syncthreads();

    const float W = (float)(*iw_p);
    const float H = (float)(*ih_p);

    // ---- decode + filter + LDS compaction (order normalized by sort below) ----
    for (int i = tid; i < N_PROP; i += 128) {
        float lc    = logit[i * NCLS + c];
        float score = expf(lc - stats[i]) * stats[N_PROP + i];

        const float4 pr = *(const float4*)(proposal + i * 4);
        float w  = pr.z - pr.x, h = pr.w - pr.y;
        float cx = pr.x + 0.5f * w, cy = pr.y + 0.5f * h;

        const float4 d = *(const float4*)(boxreg + (size_t)i * (NCLS * 4) + c * 4);
        float dx = d.x / 10.0f;
        float dy = d.y / 10.0f;
        float dw = fminf(d.z / 5.0f, BBOX_CLIP);
        float dh = fminf(d.w / 5.0f, BBOX_CLIP);
        float pcx = dx * w + cx, pcy = dy * h + cy;
        float pw  = expf(dw) * w, ph = expf(dh) * h;
        float x1 = pcx - 0.5f * pw, y1 = pcy - 0.5f * ph;
        float x2 = pcx + 0.5f * pw, y2 = pcy + 0.5f * ph;
        x1 = fminf(fmaxf(x1, 0.0f), W);
        x2 = fminf(fmaxf(x2, 0.0f), W);
        y1 = fminf(fmaxf(y1, 0.0f), H);
        y2 = fminf(fmaxf(y2, 0.0f), H);

        bool valid = (score >= SCORE_TH) && ((x2 - x1) >= MIN_SIZE) && ((y2 - y1) >= MIN_SIZE);
        if (valid) {
            int pos = atomicAdd(&s_cnt, 1);      // LDS atomic; pos < N_PROP guaranteed
            s_key[pos] = score;
            s_idx[pos] = i;
            s_box[pos] = make_float4(x1, y1, x2, y2);
        }
    }
    __syncthreads();
    const int V = s_cnt;

    // ---- rank sort: descending score, ties by ascending original index ----
    for (int t = tid; t < V; t += 128) {
        float kt = s_key[t];
        int   it = s_idx[t];
        int rank = 0;
        for (int j = 0; j < V; ++j) {
            float kj = s_key[j];
            rank += (kj > kt) || (kj == kt && s_idx[j] < it);
        }
        s_skey[rank] = kt;
        s_sbox[rank] = s_box[t];
        s_keep[rank] = 1;
    }
    __syncthreads();

    // ---- greedy NMS over sorted entries ----
    for (int i = 0; i + 1 < V; ++i) {
        if (s_keep[i]) {
            float4 bi = s_sbox[i];
            float areai = (bi.z - bi.x) * (bi.w - bi.y);
            for (int t = i + 1 + tid; t < V; t += 128) {
                if (s_keep[t]) {
                    float4 bj = s_sbox[t];
                    float lx = fmaxf(bi.x, bj.x), ly = fmaxf(bi.y, bj.y);
                    float rx = fminf(bi.z, bj.z), ry = fminf(bi.w, bj.w);
                    float iw = fmaxf(rx - lx, 0.0f), ihh = fmaxf(ry - ly, 0.0f);
                    float inter = iw * ihh;
                    float areaj = (bj.z - bj.x) * (bj.w - bj.y);
                    float uni = areai + areaj - inter;
                    float iou = inter / fmaxf(uni, 1e-6f);
                    if (iou > NMS_TH) s_keep[t] = 0;
                }
            }
        }
        __syncthreads();
    }

    if (tid == 0) {
        int cnt = 0;
        for (int t = 0; t < V && cnt < KDET; ++t)
            if (s_keep[t]) s_outpos[cnt++] = t;
        s_nout = cnt;
    }
    __syncthreads();
    const int nout = s_nout;

    // ---- write output: dets [9000,5] then labels [9000] (as float) ----
    float* dets   = out;
    float* labels = out + NCM1 * KDET * 5;
    const int rowbase = cm1 * KDET;
    for (int t = tid; t < KDET; t += 128) {
        float x1 = 0.f, y1 = 0.f, x2 = 0.f, y2 = 0.f, sc = 0.f, lb = 0.f;
        if (t < nout) {
            int p = s_outpos[t];
            float4 b = s_sbox[p];
            x1 = b.x; y1 = b.y; x2 = b.z; y2 = b.w;
            sc = s_skey[p];
            lb = (float)c;
        }
        float* r = dets + (size_t)(rowbase + t) * 5;
        r[0] = x1; r[1] = y1; r[2] = x2; r[3] = y2; r[4] = sc;
        labels[rowbase + t] = lb;
    }
}

extern "C" void kernel_launch(void* const* d_in, const int* in_sizes, int n_in,
                              void* d_out, int out_size, void* d_ws, size_t ws_size,
                              hipStream_t stream) {
    const float* logit    = (const float*)d_in[0];
    const float* boxreg   = (const float*)d_in[1];
    const float* proposal = (const float*)d_in[2];
    const int*   ih       = (const int*)d_in[3];
    const int*   iw       = (const int*)d_in[4];
    float* stats = (float*)d_ws;   // 2*N_PROP floats

    // 1000 waves (one per row) -> 250 blocks of 256
    stats_kernel<<<250, 256, 0, stream>>>(logit, stats);
    class_kernel<<<NCM1, 128, 0, stream>>>(logit, boxreg, proposal, ih, iw,
                                           stats, (float*)d_out);
}